// Round 4
// baseline (71.795 us; speedup 1.0000x reference)
//
#include <hip/hip_runtime.h>

#define BATCH 524288
#define TPB 256

typedef float vfloat16 __attribute__((ext_vector_type(16)));

// ---------------------------------------------------------------------------
// Kernel 1 (tiny): build the weight-only 16x16 unitary U into d_ws row-major:
// ws[j*32 + k] = Re U[j][k], ws[j*32 + 16 + k] = Im U[j][k].
// Thread k evolves basis state e_k (column k); writes transposed -> rows.
// ---------------------------------------------------------------------------
__global__ void qprep_kernel(const float* __restrict__ w, float* __restrict__ ws) {
    const int tid = threadIdx.x;
    if (tid >= 16) return;

    float stx[16], sty[16];
    #pragma unroll
    for (int i = 0; i < 16; i++) { stx[i] = 0.f; sty[i] = 0.f; }
    stx[tid] = 1.f;

    #pragma unroll
    for (int l = 0; l < 2; l++) {
        #pragma unroll
        for (int q = 0; q < 4; q++) {
            const float tz = 0.5f * w[l * 8 + q * 2 + 0];
            const float ty = 0.5f * w[l * 8 + q * 2 + 1];
            const float cz = __cosf(tz), sz = __sinf(tz);
            const float cy = __cosf(ty), sy = __sinf(ty);
            const int mask = 8 >> q;
            // RZ(t) = diag(e^{-it/2}, e^{+it/2})
            #pragma unroll
            for (int i = 0; i < 16; i++) {
                float ax = stx[i], ay = sty[i];
                if (i & mask) { stx[i] = ax * cz - ay * sz; sty[i] = ay * cz + ax * sz; }
                else          { stx[i] = ax * cz + ay * sz; sty[i] = ay * cz - ax * sz; }
            }
            // RY(t) = [[c,-s],[s,c]]
            #pragma unroll
            for (int i = 0; i < 16; i++) {
                if (!(i & mask)) {
                    float a0x = stx[i], a0y = sty[i];
                    float a1x = stx[i | mask], a1y = sty[i | mask];
                    stx[i]        = cy * a0x - sy * a1x;
                    sty[i]        = cy * a0y - sy * a1y;
                    stx[i | mask] = sy * a0x + cy * a1x;
                    sty[i | mask] = sy * a0y + cy * a1y;
                }
            }
        }
        // CNOT ring (0,1),(1,2),(2,3),(3,0); wire 0 is MSB (bit 3)
        #pragma unroll
        for (int e = 0; e < 4; e++) {
            const int cqs[4] = {0, 1, 2, 3};
            const int tqs[4] = {1, 2, 3, 0};
            const int cm = 8 >> cqs[e];
            const int tm = 8 >> tqs[e];
            #pragma unroll
            for (int i = 0; i < 16; i++) {
                if ((i & cm) && !(i & tm)) {
                    float t0x = stx[i], t0y = sty[i];
                    stx[i] = stx[i | tm]; sty[i] = sty[i | tm];
                    stx[i | tm] = t0x;    sty[i | tm] = t0y;
                }
            }
        }
    }
    #pragma unroll
    for (int j = 0; j < 16; j++) {
        ws[j * 32 + tid]      = stx[j];   // Re U[j][tid]
        ws[j * 32 + 16 + tid] = sty[j];   // Im U[j][tid]
    }
}

// ---------------------------------------------------------------------------
// Kernel 2 (hot): one sample per thread. U rows are pulled into SGPRs via
// explicit s_load_dwordx16 (wave-uniform address, scalar cache) so the inner
// loop is pure v_fma with an SGPR operand — zero vector-memory traffic for U.
// ---------------------------------------------------------------------------
__global__ __launch_bounds__(TPB, 8) void qmain_kernel(const float* __restrict__ x,
                                                       const float* __restrict__ U,
                                                       float* __restrict__ out) {
    const int base = blockIdx.x * TPB + threadIdx.x;

    const float4 xv = reinterpret_cast<const float4*>(x)[base];
    const float h0 = 0.5f * xv.x, h1 = 0.5f * xv.y, h2 = 0.5f * xv.z, h3 = 0.5f * xv.w;
    const float c0 = __cosf(h0), s0 = __sinf(h0);
    const float c1 = __cosf(h1), s1 = __sinf(h1);
    const float c2 = __cosf(h2), s2 = __sinf(h2);
    const float c3 = __cosf(h3), s3 = __sinf(h3);

    const float p01[4] = {c0 * c1, c0 * s1, s0 * c1, s0 * s1};
    const float p23[4] = {c2 * c3, c2 * s3, s2 * c3, s2 * s3};
    float sv[16];
    #pragma unroll
    for (int i = 0; i < 16; i++) sv[i] = p01[i >> 2] * p23[i & 3];

    float z0 = 0.f, z1 = 0.f, z2 = 0.f, z3 = 0.f;

    #pragma unroll
    for (int j = 0; j < 16; j++) {
        vfloat16 ur, ui;
        // Row j of U (Re then Im), 128 B apart; wave-uniform address -> SGPRs.
        // waitcnt inside: compiler does not track inline-asm smem loads.
        asm volatile("s_load_dwordx16 %0, %2, 0x0\n\t"
                     "s_load_dwordx16 %1, %2, 0x40\n\t"
                     "s_waitcnt lgkmcnt(0)"
                     : "=s"(ur), "=s"(ui)
                     : "s"(U + j * 32));
        float re = 0.f, im = 0.f;
        #pragma unroll
        for (int k = 0; k < 16; k++) {
            re = fmaf(ur[k], sv[k], re);
            im = fmaf(ui[k], sv[k], im);
        }
        const float p = re * re + im * im;
        z0 += (j & 8) ? -p : p;
        z1 += (j & 4) ? -p : p;
        z2 += (j & 2) ? -p : p;
        z3 += (j & 1) ? -p : p;
    }

    reinterpret_cast<float4*>(out)[base] = make_float4(z0, z1, z2, z3);
}

extern "C" void kernel_launch(void* const* d_in, const int* in_sizes, int n_in,
                              void* d_out, int out_size, void* d_ws, size_t ws_size,
                              hipStream_t stream) {
    const float* x = (const float*)d_in[0];
    const float* w = (const float*)d_in[1];
    float* out = (float*)d_out;
    float* U = (float*)d_ws;  // 512 floats, 128B-row layout

    qprep_kernel<<<1, 64, 0, stream>>>(w, U);
    qmain_kernel<<<BATCH / TPB, TPB, 0, stream>>>(x, U, out);  // 2048 blocks
}

// Round 5
// 71.692 us; speedup vs baseline: 1.0014x; 1.0014x over previous
//
#include <hip/hip_runtime.h>

#define BATCH 524288
#define TPB 256

typedef float vfloat16 __attribute__((ext_vector_type(16)));

// ---------------------------------------------------------------------------
// Kernel 1 (tiny): build the weight-only 16x16 unitary U into d_ws row-major:
// ws[j*32 + k] = Re U[j][k], ws[j*32 + 16 + k] = Im U[j][k].
// Thread k evolves basis state e_k (column k); writes transposed -> rows.
// ---------------------------------------------------------------------------
__global__ void qprep_kernel(const float* __restrict__ w, float* __restrict__ ws) {
    const int tid = threadIdx.x;
    if (tid >= 16) return;

    float stx[16], sty[16];
    #pragma unroll
    for (int i = 0; i < 16; i++) { stx[i] = 0.f; sty[i] = 0.f; }
    stx[tid] = 1.f;

    #pragma unroll
    for (int l = 0; l < 2; l++) {
        #pragma unroll
        for (int q = 0; q < 4; q++) {
            const float tz = 0.5f * w[l * 8 + q * 2 + 0];
            const float ty = 0.5f * w[l * 8 + q * 2 + 1];
            const float cz = __cosf(tz), sz = __sinf(tz);
            const float cy = __cosf(ty), sy = __sinf(ty);
            const int mask = 8 >> q;
            // RZ(t) = diag(e^{-it/2}, e^{+it/2})
            #pragma unroll
            for (int i = 0; i < 16; i++) {
                float ax = stx[i], ay = sty[i];
                if (i & mask) { stx[i] = ax * cz - ay * sz; sty[i] = ay * cz + ax * sz; }
                else          { stx[i] = ax * cz + ay * sz; sty[i] = ay * cz - ax * sz; }
            }
            // RY(t) = [[c,-s],[s,c]]
            #pragma unroll
            for (int i = 0; i < 16; i++) {
                if (!(i & mask)) {
                    float a0x = stx[i], a0y = sty[i];
                    float a1x = stx[i | mask], a1y = sty[i | mask];
                    stx[i]        = cy * a0x - sy * a1x;
                    sty[i]        = cy * a0y - sy * a1y;
                    stx[i | mask] = sy * a0x + cy * a1x;
                    sty[i | mask] = sy * a0y + cy * a1y;
                }
            }
        }
        // CNOT ring (0,1),(1,2),(2,3),(3,0); wire 0 is MSB (bit 3)
        #pragma unroll
        for (int e = 0; e < 4; e++) {
            const int cqs[4] = {0, 1, 2, 3};
            const int tqs[4] = {1, 2, 3, 0};
            const int cm = 8 >> cqs[e];
            const int tm = 8 >> tqs[e];
            #pragma unroll
            for (int i = 0; i < 16; i++) {
                if ((i & cm) && !(i & tm)) {
                    float t0x = stx[i], t0y = sty[i];
                    stx[i] = stx[i | tm]; sty[i] = sty[i | tm];
                    stx[i | tm] = t0x;    sty[i | tm] = t0y;
                }
            }
        }
    }
    #pragma unroll
    for (int j = 0; j < 16; j++) {
        ws[j * 32 + tid]      = stx[j];   // Re U[j][tid]
        ws[j * 32 + 16 + tid] = sty[j];   // Im U[j][tid]
    }
}

// ---------------------------------------------------------------------------
// Kernel 2 (hot): one sample per thread. U rows pulled into SGPRs via explicit
// s_load_dwordx16 (wave-uniform, scalar cache); inner loop is v_fma with SGPR
// operand. launch_bounds(256,4): 128-VGPR cap — NO spill risk (R4's (256,8)
// capped at 64 VGPRs and likely spilled sv[16]+friends to scratch).
// ---------------------------------------------------------------------------
__global__ __launch_bounds__(TPB, 4) void qmain_kernel(const float* __restrict__ x,
                                                       const float* __restrict__ U,
                                                       float* __restrict__ out) {
    const int base = blockIdx.x * TPB + threadIdx.x;

    const float4 xv = reinterpret_cast<const float4*>(x)[base];
    const float h0 = 0.5f * xv.x, h1 = 0.5f * xv.y, h2 = 0.5f * xv.z, h3 = 0.5f * xv.w;
    const float c0 = __cosf(h0), s0 = __sinf(h0);
    const float c1 = __cosf(h1), s1 = __sinf(h1);
    const float c2 = __cosf(h2), s2 = __sinf(h2);
    const float c3 = __cosf(h3), s3 = __sinf(h3);

    const float p01[4] = {c0 * c1, c0 * s1, s0 * c1, s0 * s1};
    const float p23[4] = {c2 * c3, c2 * s3, s2 * c3, s2 * s3};
    float sv[16];
    #pragma unroll
    for (int i = 0; i < 16; i++) sv[i] = p01[i >> 2] * p23[i & 3];

    float z0 = 0.f, z1 = 0.f, z2 = 0.f, z3 = 0.f;

    #pragma unroll
    for (int j = 0; j < 16; j++) {
        vfloat16 ur, ui;
        // Row j of U (Re then Im), 128 B apart; wave-uniform address -> SGPRs.
        // waitcnt inside: compiler does not track inline-asm smem loads.
        asm volatile("s_load_dwordx16 %0, %2, 0x0\n\t"
                     "s_load_dwordx16 %1, %2, 0x40\n\t"
                     "s_waitcnt lgkmcnt(0)"
                     : "=s"(ur), "=s"(ui)
                     : "s"(U + j * 32));
        float re = 0.f, im = 0.f;
        #pragma unroll
        for (int k = 0; k < 16; k++) {
            re = fmaf(ur[k], sv[k], re);
            im = fmaf(ui[k], sv[k], im);
        }
        const float p = re * re + im * im;
        z0 += (j & 8) ? -p : p;
        z1 += (j & 4) ? -p : p;
        z2 += (j & 2) ? -p : p;
        z3 += (j & 1) ? -p : p;
    }

    reinterpret_cast<float4*>(out)[base] = make_float4(z0, z1, z2, z3);
}

extern "C" void kernel_launch(void* const* d_in, const int* in_sizes, int n_in,
                              void* d_out, int out_size, void* d_ws, size_t ws_size,
                              hipStream_t stream) {
    const float* x = (const float*)d_in[0];
    const float* w = (const float*)d_in[1];
    float* out = (float*)d_out;
    float* U = (float*)d_ws;  // 512 floats, 128B-row layout

    qprep_kernel<<<1, 64, 0, stream>>>(w, U);
    qmain_kernel<<<BATCH / TPB, TPB, 0, stream>>>(x, U, out);  // 2048 blocks
}